// Round 8
// baseline (536.320 us; speedup 1.0000x reference)
//
#include <hip/hip_runtime.h>
#include <hip/hip_bf16.h>

#define Hh 256
#define Ii 128
#define KF 384    // 128 (x) + 256 (hx) feature dim
#define LDSB 72   // sP padded stride (bf16 elems)
#define SBN 392   // sB padded stride (bf16 elems), 784 B rows (16B-aligned)

typedef __attribute__((ext_vector_type(8))) short bf16x8;
typedef __attribute__((ext_vector_type(4))) float f32x4;
typedef unsigned short u16;
typedef unsigned int u32;

__device__ inline u16 f2bf(float f) {
  u32 u = __float_as_uint(f);
  u += 0x7FFFu + ((u >> 16) & 1u);   // RNE
  return (u16)(u >> 16);
}
__device__ inline u32 pack_bf16x2(float a, float b) {
  __hip_bfloat162 h = __float22bfloat162_rn(make_float2(a, b));
  u32 r; __builtin_memcpy(&r, &h, 4); return r;
}
// scale packed bf16 pair by (va, vb), repack
__device__ inline u32 scale2(u32 packed, float va, float vb) {
  float lo = __uint_as_float(packed << 16) * va;
  float hi = __uint_as_float(packed & 0xFFFF0000u) * vb;
  return pack_bf16x2(lo, hi);
}
__device__ inline float sigm(float x) { return 1.0f / (1.0f + __expf(-x)); }
__device__ inline float tanh_f(float x) { return 1.0f - 2.0f / (1.0f + __expf(2.0f * x)); }

union U32x4 { bf16x8 f; u32 d[4]; uint4 v; };

// ---------------- kernel 0: pack weights (gather / coalesced-store) ---------
// Layouts: RWp[ph][kc][j][64] ; CWp[ph][kb][kc][k64][64] ; WoT[t][h]
__global__ __launch_bounds__(256) void k_prep(
    const float* __restrict__ Wii, const float* __restrict__ Wif, const float* __restrict__ Wig,
    const float* __restrict__ Whi, const float* __restrict__ Whit,
    const float* __restrict__ Whf, const float* __restrict__ Whft,
    const float* __restrict__ Whc, const float* __restrict__ Whct,
    const float* __restrict__ Vtinv, const float* __restrict__ Uinv,
    const float* __restrict__ Wio, const float* __restrict__ Who,
    u16* __restrict__ RW, u16* __restrict__ CW, u16* __restrict__ Vtt,
    float* __restrict__ UinvP, float* __restrict__ proj, float* __restrict__ WoT) {
  const int tid = threadIdx.x, bx = blockIdx.x, y = blockIdx.y;
  if (y < 3) {
    // RW phase y: f = kc*16384 + h*64 + t0 ; t = kc*64 + t0
    if (bx < 48) {
      const float* WX  = (y == 0) ? Wii : (y == 1 ? Wif : Wig);
      const float* WHr = (y == 0) ? Whi : (y == 1 ? Whf : Whc);
      u16* rw = RW + y * Hh * KF;
      const int f  = (bx * 256 + tid) * 8;
      const int kc = f >> 14;
      const int h  = (f >> 6) & 255;
      const int t0 = f & 63;
      const float* src = (kc < 2) ? (WX + h * Ii + kc * 64 + t0)
                                  : (WHr + h * Hh + (kc - 2) * 64 + t0);
      const float4 s0 = *(const float4*)src;
      const float4 s1 = *(const float4*)(src + 4);
      uint4 o;
      o.x = (u32)f2bf(s0.x) | ((u32)f2bf(s0.y) << 16);
      o.y = (u32)f2bf(s0.z) | ((u32)f2bf(s0.w) << 16);
      o.z = (u32)f2bf(s1.x) | ((u32)f2bf(s1.y) << 16);
      o.w = (u32)f2bf(s1.z) | ((u32)f2bf(s1.w) << 16);
      *(uint4*)(rw + f) = o;
    }
  } else if (y < 6) {
    // CW phase y-3: f = kb*24576 + kc*4096 + k*64 + t0 ; h = kb*64+k
    if (bx < 48) {
      const int ph = y - 3;
      const float* WX  = (ph == 0) ? Wii : (ph == 1 ? Wif : Wig);
      const float* WHt = (ph == 0) ? Whit : (ph == 1 ? Whft : Whct);
      u16* cw = CW + ph * Hh * KF;
      const int f  = (bx * 256 + tid) * 8;
      const int kb = f / 24576;
      const int r  = f - kb * 24576;
      const int kc = r >> 12;
      const int r2 = r & 4095;
      const int k  = r2 >> 6;
      const int t0 = r2 & 63;
      const int h  = kb * 64 + k;
      const float* src = (kc < 2) ? (WX + h * Ii + kc * 64 + t0)
                                  : (WHt + h * Hh + (kc - 2) * 64 + t0);
      const float4 s0 = *(const float4*)src;
      const float4 s1 = *(const float4*)(src + 4);
      uint4 o;
      o.x = (u32)f2bf(s0.x) | ((u32)f2bf(s0.y) << 16);
      o.y = (u32)f2bf(s0.z) | ((u32)f2bf(s0.w) << 16);
      o.z = (u32)f2bf(s1.x) | ((u32)f2bf(s1.y) << 16);
      o.w = (u32)f2bf(s1.z) | ((u32)f2bf(s1.w) << 16);
      *(uint4*)(cw + f) = o;
    }
  } else if (y == 6) {
    if (bx < 64) {
      // Vtt[i][k] = Vtinv[k][i], 32x32 LDS tile transpose
      __shared__ u16 tbuf[32][33];
      const int c = tid & 31, r8 = tid >> 5;
      const int tr = bx >> 3, tc = bx & 7;
#pragma unroll
      for (int rr = r8; rr < 32; rr += 8)
        tbuf[rr][c] = f2bf(Vtinv[(tc * 32 + rr) * Hh + tr * 32 + c]);
      __syncthreads();
#pragma unroll
      for (int rr = r8; rr < 32; rr += 8)
        Vtt[(tr * 32 + rr) * Hh + tc * 32 + c] = tbuf[c][rr];
    } else {
      // WoT[t][h] = o-gate weight (h,t): coalesced writes across tid=h
      const int tb = (bx - 64) * 12;
#pragma unroll
      for (int tt = 0; tt < 12; ++tt) {
        const int t = tb + tt;
        const float v = (t < Ii) ? Wio[tid * Ii + t] : Who[tid * Hh + t - Ii];
        WoT[t * Hh + tid] = v;
      }
    }
  } else {
    if (bx < 32) {
      // UinvP: f = tid512*128 + e ; e = ti*32 + tjl*4 + r
      const int base = (bx * 256 + tid) * 8;
#pragma unroll
      for (int e8 = 0; e8 < 8; ++e8) {
        int f = base + e8;                  // 0..65535
        int t512 = f >> 7;
        int e = f & 127;
        int ti = e >> 5;
        int rem = e & 31;
        int tjl = rem >> 2;
        int rr = rem & 3;
        int wv = t512 >> 6;
        int ln = t512 & 63;
        int qd = ln >> 4;
        int r15v = ln & 15;
        int i = (wv & 3) * 64 + ti * 16 + qd * 4 + rr;
        int j = (wv >> 2) * 128 + tjl * 16 + r15v;
        UinvP[f] = Uinv[i * Hh + j];
      }
    } else if (bx < 64) {
      const int base = (bx - 32) * 256 + tid;
      const float4 z = {0.f, 0.f, 0.f, 0.f};
#pragma unroll
      for (int it = 0; it < 4; ++it)
        *(float4*)(proj + (size_t)(it * 8192 + base) * 4) = z;
    }
  }
}

// ---------------- kernel 1: fused gates + cell + down-projection -------------
// grid 2048 = b(512) x kb(4); 512 threads = 8 waves; wave owns 32 j-rows.
// R8: PHASE-GRANULAR staging. R0-R6 all pinned at ~350-373us: 18 barrier
// intervals each costing ~6.2k cyc to deliver ~620 cyc of MFMA (MfmaUtil
// 10.4% matches exactly). Fix the cadence, not the loads: stage the WHOLE
// phase K-dim (64 k x 384 t, 49KB) per barrier pair -> 96 MFMA/wave of
// sync-free compute per phase (6x more per barrier, 19 -> 9 barriers).
// Next-phase CW loads issue mid-compute (kc==3): L2 latency under MFMA.
// sP unions over sB (dead after last phase read, fenced by barrier).
// NOTE: no min-waves launch_bounds arg (R1 spill lesson). Spill tripwire:
// FETCH_SIZE ~74 MB, VGPR target <=168.
__global__ __launch_bounds__(512) void k_main(
    const float* __restrict__ x, const float* __restrict__ hx, const float* __restrict__ cx,
    const u16* __restrict__ RW, const u16* __restrict__ CW, const u16* __restrict__ Vtt,
    const float* __restrict__ bi, const float* __restrict__ bfm, const float* __restrict__ bg,
    const float* __restrict__ UinvP, float* __restrict__ proj) {
  __shared__ union {
    u16 B[64][SBN];       // 50176 B scaled-B, full phase (64 k-rows x 384 t)
    u16 P[256][LDSB];     // 36864 B c-tile (256 j x 64 k)
  } sU;
  __shared__ float sV[KF];        // 1536 B
  __shared__ float sPart[8][64];  // 2048 B

  const int tid  = threadIdx.x;
  const int b    = blockIdx.x >> 2;
  const int kb   = blockIdx.x & 3;
  const int k0   = kb * 64;
  const int lane = tid & 63;
  const int w    = tid >> 6;
  const int r15  = lane & 15;
  const int quad = lane >> 4;
  const int srow = tid >> 3;       // staging row 0..63
  const int scol = (tid & 7) * 8;  // staging col within chunk

  if (tid < Ii) sV[tid] = x[b * Ii + tid];
  if (tid < Hh) sV[Ii + tid] = hx[b * Hh + tid];

  // phase order: g (tanh), i, f
  const u16* rwp[3] = {RW + 2 * Hh * KF, RW, RW + 1 * Hh * KF};
  const u16* cwp[3] = {CW + 2 * Hh * KF + kb * 24576, CW + kb * 24576,
                       CW + 1 * Hh * KF + kb * 24576};
  const float* bp3[2] = {bg, bi};
  const float* cx_b = cx + (size_t)b * Hh * Hh;

  // wf base: chunk-major row = (w*32 + ja*16 + r15), 64 elems per row
  const int wfoff = (w * 32 + r15) * 64 + quad * 8;

  // prologue: issue phase-0 staging loads (independent of sV)
  U32x4 L[6];
#pragma unroll
  for (int kc = 0; kc < 6; ++kc)
    L[kc].v = *(const uint4*)(cwp[0] + kc * 4096 + tid * 8);
  __syncthreads();   // sV ready
#pragma unroll
  for (int kc = 0; kc < 6; ++kc) {
    U32x4 o;
    const float4 va = *(const float4*)(&sV[kc * 64 + scol]);
    const float4 vb = *(const float4*)(&sV[kc * 64 + scol + 4]);
    o.d[0] = scale2(L[kc].d[0], va.x, va.y); o.d[1] = scale2(L[kc].d[1], va.z, va.w);
    o.d[2] = scale2(L[kc].d[2], vb.x, vb.y); o.d[3] = scale2(L[kc].d[3], vb.z, vb.w);
    *(uint4*)(&sU.B[srow][kc * 64 + scol]) = o.v;
  }
  __syncthreads();   // sB(phase 0) ready

  float p[2][4][4];
  f32x4 acc[2][4];

#pragma unroll
  for (int ph = 0; ph < 3; ++ph) {
#pragma unroll
    for (int ja = 0; ja < 2; ++ja)
#pragma unroll
      for (int tk = 0; tk < 4; ++tk)
#pragma unroll
        for (int r = 0; r < 4; ++r) acc[ja][tk][r] = 0.0f;

    // ---- phase compute: 6 chunks, NO barriers between chunks ----
#pragma unroll
    for (int kc = 0; kc < 6; ++kc) {
      // issue next-phase staging loads mid-compute (latency under MFMA)
      if (ph < 2 && kc == 3) {
#pragma unroll
        for (int k2 = 0; k2 < 6; ++k2)
          L[k2].v = *(const uint4*)(cwp[ph + 1] + k2 * 4096 + tid * 8);
      }
      bf16x8 wf[2][2];
      {
        const u16* rb = rwp[ph] + kc * 16384 + wfoff;
#pragma unroll
        for (int ja = 0; ja < 2; ++ja)
#pragma unroll
          for (int ks = 0; ks < 2; ++ks)
            wf[ja][ks] = *(const bf16x8*)(rb + ja * 1024 + ks * 32);
      }
#pragma unroll
      for (int ks = 0; ks < 2; ++ks) {
        bf16x8 sf[4];
#pragma unroll
        for (int tk = 0; tk < 4; ++tk)
          sf[tk] = *(const bf16x8*)(&sU.B[tk * 16 + r15][kc * 64 + ks * 32 + quad * 8]);
#pragma unroll
        for (int tk = 0; tk < 4; ++tk) {
          acc[0][tk] = __builtin_amdgcn_mfma_f32_16x16x32_bf16(sf[tk], wf[0][ks], acc[0][tk], 0, 0, 0);
          acc[1][tk] = __builtin_amdgcn_mfma_f32_16x16x32_bf16(sf[tk], wf[1][ks], acc[1][tk], 0, 0, 0);
        }
      }
    }

    if (ph < 2) {
      // combine into p (registers only)
      const float* bp = bp3[ph];
#pragma unroll
      for (int ja = 0; ja < 2; ++ja) {
        const int jg = w * 32 + ja * 16 + r15;
        const float* bpr = bp + (size_t)jg * Hh + k0 + quad * 4;
#pragma unroll
        for (int tk = 0; tk < 4; ++tk) {
          const float4 bv = *(const float4*)(bpr + tk * 16);
          if (ph == 0) {
#pragma unroll
            for (int r = 0; r < 4; ++r)
              p[ja][tk][r] = tanh_f(acc[ja][tk][r] + ((const float*)&bv)[r]);
          } else {
#pragma unroll
            for (int r = 0; r < 4; ++r)
              p[ja][tk][r] *= sigm(acc[ja][tk][r] + ((const float*)&bv)[r]);
          }
        }
      }
      __syncthreads();   // all reads of sB(ph) done
#pragma unroll
      for (int kc = 0; kc < 6; ++kc) {
        U32x4 o;
        const float4 va = *(const float4*)(&sV[kc * 64 + scol]);
        const float4 vb = *(const float4*)(&sV[kc * 64 + scol + 4]);
        o.d[0] = scale2(L[kc].d[0], va.x, va.y); o.d[1] = scale2(L[kc].d[1], va.z, va.w);
        o.d[2] = scale2(L[kc].d[2], vb.x, vb.y); o.d[3] = scale2(L[kc].d[3], vb.z, vb.w);
        *(uint4*)(&sU.B[srow][kc * 64 + scol]) = o.v;
      }
      __syncthreads();   // sB(ph+1) ready
    }
  }

  // ---- ph2 (f-gate) combine: barrier, then sU.B dead -> write sU.P ----
  __syncthreads();
#pragma unroll
  for (int ja = 0; ja < 2; ++ja) {
    const int jg = w * 32 + ja * 16 + r15;
    const float* bpr = bfm + (size_t)jg * Hh + k0 + quad * 4;
    const float* cxr = cx_b + (size_t)jg * Hh + k0 + quad * 4;
#pragma unroll
    for (int tk = 0; tk < 4; ++tk) {
      const float4 bv = *(const float4*)(bpr + tk * 16);
      const float4 cv = *(const float4*)(cxr + tk * 16);
      float cc[4];
#pragma unroll
      for (int r = 0; r < 4; ++r)
        cc[r] = sigm(acc[ja][tk][r] + ((const float*)&bv)[r]) * ((const float*)&cv)[r] + p[ja][tk][r];
      uint2 pk;
      pk.x = pack_bf16x2(cc[0], cc[1]);
      pk.y = pack_bf16x2(cc[2], cc[3]);
      *(uint2*)(&sU.P[jg][tk * 16 + quad * 4]) = pk;
    }
  }
  __syncthreads();

  // ---- projection: M[i,j] = sum_k Vtt[i,k] c[j,k]; racc[i] += M[i,j]*Uinv[i,j]
  //      wave: i-slab = (w&3)*64, j-half = (w>>2)*128 .. +128
  const int islab = (w & 3) * 64;
  const int jhb   = (w >> 2) * 128;
  const float* up = UinvP + (size_t)tid * 128;
  float racc[4][4];
#pragma unroll
  for (int ti = 0; ti < 4; ++ti)
#pragma unroll
    for (int r = 0; r < 4; ++r) racc[ti][r] = 0.0f;

#pragma unroll
  for (int tjg = 0; tjg < 2; ++tjg) {
    bf16x8 fbp[2][4];
#pragma unroll
    for (int ks = 0; ks < 2; ++ks)
#pragma unroll
      for (int tjj = 0; tjj < 4; ++tjj)
        fbp[ks][tjj] = *(const bf16x8*)(&sU.P[jhb + (tjg * 4 + tjj) * 16 + r15][ks * 32 + quad * 8]);
#pragma unroll
    for (int ti = 0; ti < 4; ++ti) {
      const u16* vrow = Vtt + (size_t)(islab + ti * 16 + r15) * Hh + k0 + quad * 8;
      const bf16x8 va0 = *(const bf16x8*)vrow;
      const bf16x8 va1 = *(const bf16x8*)(vrow + 32);
      f32x4 pacc[4];
#pragma unroll
      for (int tjj = 0; tjj < 4; ++tjj)
#pragma unroll
        for (int r = 0; r < 4; ++r) pacc[tjj][r] = 0.0f;
#pragma unroll
      for (int tjj = 0; tjj < 4; ++tjj)
        pacc[tjj] = __builtin_amdgcn_mfma_f32_16x16x32_bf16(va0, fbp[0][tjj], pacc[tjj], 0, 0, 0);
#pragma unroll
      for (int tjj = 0; tjj < 4; ++tjj)
        pacc[tjj] = __builtin_amdgcn_mfma_f32_16x16x32_bf16(va1, fbp[1][tjj], pacc[tjj], 0, 0, 0);
#pragma unroll
      for (int tjj = 0; tjj < 4; ++tjj) {
        const float4 uu = *(const float4*)(up + ti * 32 + (tjg * 4 + tjj) * 4);
#pragma unroll
        for (int r = 0; r < 4; ++r)
          racc[ti][r] += pacc[tjj][r] * ((const float*)&uu)[r];
      }
    }
  }

#pragma unroll
  for (int ti = 0; ti < 4; ++ti)
#pragma unroll
    for (int r = 0; r < 4; ++r) {
      float v = racc[ti][r];
      v += __shfl_xor(v, 1);
      v += __shfl_xor(v, 2);
      v += __shfl_xor(v, 4);
      v += __shfl_xor(v, 8);
      if (r15 == 0) sPart[w][ti * 16 + quad * 4 + r] = v;
    }
  __syncthreads();
  if (tid < Hh)
    atomicAdd(&proj[b * Hh + tid], sPart[tid >> 6][tid & 63] + sPart[(tid >> 6) + 4][tid & 63]);
}

// ---------------- kernel 2: o-gate + final output ---------------------------
__global__ __launch_bounds__(256) void k_out(
    const float* __restrict__ x, const float* __restrict__ hx,
    const float* __restrict__ WoT, const float* __restrict__ bo,
    const float* __restrict__ proj, float* __restrict__ out) {
  __shared__ float sv[KF];
  const int b = blockIdx.x, tid = threadIdx.x;
  if (tid < Ii) sv[tid] = x[b * Ii + tid];
  sv[Ii + tid] = hx[b * Hh + tid];
  __syncthreads();
  float acc = 0.0f;
  const float* wp = WoT + tid;
#pragma unroll 16
  for (int t = 0; t < KF; ++t)
    acc = fmaf(sv[t], wp[(size_t)t * Hh], acc);
  out[b * Hh + tid] = sigm(acc + bo[tid]) * sigm(proj[b * Hh + tid]);
}

extern "C" void kernel_launch(void* const* d_in, const int* in_sizes, int n_in,
                              void* d_out, int out_size, void* d_ws, size_t ws_size,
                              hipStream_t stream) {
  (void)in_sizes; (void)n_in; (void)out_size; (void)ws_size;
  const float* x    = (const float*)d_in[0];
  const float* hx   = (const float*)d_in[1];
  const float* cx   = (const float*)d_in[2];
  const float* Wii  = (const float*)d_in[3];
  const float* Wif  = (const float*)d_in[4];
  const float* Wig  = (const float*)d_in[5];
  const float* Wio  = (const float*)d_in[6];
  const float* Whi  = (const float*)d_in[7];
  const float* Whit = (const float*)d_in[8];
  const float* Whf  = (const float*)d_in[9];
  const float* Whft = (const float*)d_in[10];
  const float* Whc  = (const float*)d_in[11];
  const float* Whct = (const float*)d_in[12];
  const float* Who  = (const float*)d_in[13];
  const float* Uinv = (const float*)d_in[14];
  const float* Vtinv= (const float*)d_in[15];
  const float* bi   = (const float*)d_in[16];
  const float* bf   = (const float*)d_in[17];
  const float* bg   = (const float*)d_in[18];
  const float* bo   = (const float*)d_in[19];
  float* out = (float*)d_out;

  // workspace (2,490,368 B): RW[3], CW[3], Vtt (bf16); UinvP, proj, WoT (f32)
  u16* RW    = (u16*)d_ws;
  u16* CW    = RW + 3 * Hh * KF;          // u16 idx 294912
  u16* Vtt   = CW + 3 * Hh * KF;          // u16 idx 589824
  float* UinvP = (float*)(Vtt + Hh * Hh); // byte 1,310,720
  float* proj  = UinvP + Hh * Hh;         // byte 1,572,864
  float* WoT   = proj + 512 * Hh;         // byte 2,097,152 (+393,216 = 2,490,368)

  k_prep<<<dim3(96, 8), 256, 0, stream>>>(Wii, Wif, Wig, Whi, Whit, Whf, Whft, Whc, Whct,
                                          Vtinv, Uinv, Wio, Who,
                                          RW, CW, Vtt, UinvP, proj, WoT);
  k_main<<<2048, 512, 0, stream>>>(x, hx, cx, RW, CW, Vtt, bi, bf, bg, UinvP, proj);
  k_out<<<512, 256, 0, stream>>>(x, hx, WoT, bo, proj, out);
}